// Round 9
// baseline (20645.346 us; speedup 1.0000x reference)
//
#include <hip/hip_runtime.h>

#define HD 512
#define BB 1024
#define TT 512
#define PP 96
#define DIN 32
#define KC_H 16
#define NBLK 256
#define GRPB 16  // blocks per row-group barrier (all 16 jb of one row group)

typedef unsigned short u16;
typedef __attribute__((ext_vector_type(8))) short bf16x8;
typedef __attribute__((ext_vector_type(4))) float f32x4;
typedef __attribute__((address_space(3))) unsigned int lds_u32;
typedef __attribute__((address_space(3))) u16 lds_u16;
typedef __attribute__((address_space(1))) unsigned int glb_u32;

#define WAIT_VM(N) asm volatile("s_waitcnt vmcnt(" #N ")" ::: "memory")
__device__ __forceinline__ void bar_raw() { asm volatile("s_barrier" ::: "memory"); }

template <int N> __device__ __forceinline__ void wvm() {
  if constexpr (N == 0) WAIT_VM(0);
  else if constexpr (N == 2) WAIT_VM(2);
  else if constexpr (N == 4) WAIT_VM(4);
  else if constexpr (N == 5) WAIT_VM(5);
  else if constexpr (N == 10) WAIT_VM(10);
  else if constexpr (N == 13) WAIT_VM(13);
}

__device__ __forceinline__ float bf2f(u16 s) {
  return __uint_as_float(((unsigned)s) << 16);
}
__device__ __forceinline__ u16 f2bf_rne(float f) {
  unsigned u = __float_as_uint(f);
  u += 0x7FFF + ((u >> 16) & 1);
  return (u16)(u >> 16);
}
__device__ __forceinline__ float sigm(float v) { return 1.f / (1.f + __expf(-v)); }
__device__ __forceinline__ float tanh_(float a) {
  return 1.f - 2.f / (__expf(2.f * a) + 1.f);
}

// ---- access helpers ----
// LOC=true : h-state traffic is XCD-local -> L2-coherent (sc0 = L1 bypass).
// LOC=false: cross-XCD fallback -> LLC-coherent (sc0 sc1), same as R8.
template <bool LOC>
__device__ __forceinline__ bf16x8 load_a16(const u16* p) {
  bf16x8 r;
  if constexpr (LOC)
    asm volatile("global_load_dwordx4 %0, %1, off sc0" : "=&v"(r) : "v"(p) : "memory");
  else
    asm volatile("global_load_dwordx4 %0, %1, off sc0 sc1" : "=&v"(r) : "v"(p) : "memory");
  return r;
}
__device__ __forceinline__ void store_h_u16(u16* p, unsigned v, bool loc) {
  if (loc)
    asm volatile("global_store_short %0, %1, off sc0" :: "v"(p), "v"(v) : "memory");
  else
    asm volatile("global_store_short %0, %1, off sc0 sc1" :: "v"(p), "v"(v) : "memory");
}
__device__ __forceinline__ void store_sc_f32(float* p, float v) {
  asm volatile("global_store_dword %0, %1, off sc0 sc1" :: "v"(p), "v"(v) : "memory");
}
__device__ __forceinline__ float load_sc_f32w(const float* p) {  // load + full wait
  float v;
  asm volatile("global_load_dword %0, %1, off sc0 sc1\ns_waitcnt vmcnt(0)"
               : "=&v"(v) : "v"(p) : "memory");
  return v;
}
__device__ __forceinline__ unsigned load_sc_u32w(const unsigned* p) {
  unsigned v;
  asm volatile("global_load_dword %0, %1, off sc0 sc1\ns_waitcnt vmcnt(0)"
               : "=&v"(v) : "v"(p) : "memory");
  return v;
}
__device__ __forceinline__ void store_h_sc(u16* H, u16* L, size_t idx, float hv,
                                           bool loc) {
  u16 hi = (u16)(__float_as_uint(hv) >> 16);  // trunc; lo corrects
  u16 lo = f2bf_rne(hv - bf2f(hi));
  store_h_u16(H + idx, (unsigned)hi, loc);
  store_h_u16(L + idx, (unsigned)lo, loc);
}

// ---- h-state layout: kc-blocked tiles (as R8) ----
// h[rowtile:64][kc:16][rr:16][cc:32] u16; element (row,col) at
// (row>>4)*8192 + (col>>5)*512 + (row&15)*32 + (col&31).

// Pack fp32 weight W[3H x K] into fc-contiguous MFMA B-frag bf16 hi/lo layout.
__global__ void pack_w_kernel(const float* __restrict__ W, int K,
                              u16* __restrict__ out) {
  int tid = blockIdx.x * 256 + threadIdx.x;
  int KC = K >> 5;
  int total = 16 * KC * 2 * 6 * 64;
  if (tid >= total) return;
  int lane = tid & 63;
  int rest = tid >> 6;
  int gs = rest % 6; rest /= 6;
  int fc = rest & 1; rest >>= 1;
  int kc = rest % KC;
  int jb = rest / KC;
  int g = gs >> 1, s = gs & 1;
  int j = jb * 32 + fc * 16 + (lane & 15);
  int k = kc * 32 + (lane >> 4) * 8;
  const float* src = W + (size_t)(g * HD + j) * K + k;
  bf16x8 v;
#pragma unroll
  for (int i = 0; i < 8; ++i) {
    float f = src[i];
    u16 hi = f2bf_rne(f);
    v[i] = (short)((s == 0) ? hi : f2bf_rne(f - bf2f(hi)));
  }
  *(bf16x8*)(out + (size_t)tid * 8) = v;
}

// A fragments for NA distinct A-streams (hi/lo split bf16).
template <int NA> struct AFN { bf16x8 h[NA]; bf16x8 l[NA]; };
template <int NA>
__device__ __forceinline__ void fence_afn(AFN<NA>& a) {
#pragma unroll
  for (int n = 0; n < NA; ++n)
    asm volatile("" : "+v"(a.h[n]), "+v"(a.l[n]));
}

// 9 MFMAs for one (stream, fc) 6KB chunk (6 frag groups of 512 u16).
__device__ __forceinline__ void mfma_kc9(const lds_u16* base, int lane,
                                         bf16x8 ah, bf16x8 al,
                                         f32x4& R, f32x4& Z, f32x4& N) {
  typedef __attribute__((address_space(3))) const bf16x8 lds_bf16x8;
  const lds_u16* p = base + lane * 8;
#pragma unroll
  for (int g = 0; g < 3; ++g) {
    f32x4* a = (g == 0) ? &R : (g == 1) ? &Z : &N;
    bf16x8 whi = *(lds_bf16x8*)(p + (g * 2 + 0) * 512);
    bf16x8 wlo = *(lds_bf16x8*)(p + (g * 2 + 1) * 512);
    *a = __builtin_amdgcn_mfma_f32_16x16x32_bf16(ah, whi, *a, 0, 0, 0);
    *a = __builtin_amdgcn_mfma_f32_16x16x32_bf16(al, whi, *a, 0, 0, 0);
    *a = __builtin_amdgcn_mfma_f32_16x16x32_bf16(ah, wlo, *a, 0, 0, 0);
  }
}
// Global variant for the K=32 x-phase (L2-hot, compiler-managed waits).
__device__ __forceinline__ void mfma_kc9_g(const u16* base, int lane,
                                           bf16x8 ah, bf16x8 al,
                                           f32x4& R, f32x4& Z, f32x4& N) {
  const u16* p = base + lane * 8;
#pragma unroll
  for (int g = 0; g < 3; ++g) {
    f32x4* a = (g == 0) ? &R : (g == 1) ? &Z : &N;
    bf16x8 whi = *(const bf16x8*)(p + (g * 2 + 0) * 512);
    bf16x8 wlo = *(const bf16x8*)(p + (g * 2 + 1) * 512);
    *a = __builtin_amdgcn_mfma_f32_16x16x32_bf16(ah, whi, *a, 0, 0, 0);
    *a = __builtin_amdgcn_mfma_f32_16x16x32_bf16(al, whi, *a, 0, 0, 0);
    *a = __builtin_amdgcn_mfma_f32_16x16x32_bf16(ah, wlo, *a, 0, 0, 0);
  }
}

// Weight-piece mapping: NS streams x 12 x 1KB pieces; each wave stages NS*3.
template <int NS>
__device__ __forceinline__ void piece_map(const u16* const (&Wjb)[NS],
                                          int lane, int wave,
                                          const u16* (&srcB)[NS * 3],
                                          int (&dstO)[NS * 3]) {
#pragma unroll
  for (int i = 0; i < NS * 3; ++i) {
    const int p = wave * (NS * 3) + i;
    const int s = p / 12, r = p % 12, f2 = r / 6, j = r % 6;
    const int co = f2 * 3072 + j * 512;
    srcB[i] = Wjb[s] + co + lane * 8;
    dstO[i] = s * 6144 + co;
  }
}

// Barrier-shadow weight prefetch for slots 0,1 (weights read-only -> legal
// before the row-group barrier completes).
template <int NS>
__device__ __forceinline__ void stageW2(u16* ringb, const u16* const (&Wjb)[NS],
                                        int lane, int wave) {
  const u16* srcB[NS * 3]; int dstO[NS * 3];
  piece_map<NS>(Wjb, lane, wave, srcB, dstO);
#pragma unroll
  for (int ikc = 0; ikc < 2; ++ikc)
#pragma unroll
    for (int i = 0; i < NS * 3; ++i)
      __builtin_amdgcn_global_load_lds(
          (const glb_u32*)(srcB[i] + (size_t)ikc * 6144),
          (lds_u32*)(ringb + (size_t)ikc * NS * 6144 + dstO[i]), 16, 0, 0);
}

// Multi-stream K=512 GEMM pipe, depth-3 ring, prefetched slots 0,1.
template <int NS, int NA, bool LOC>
__device__ __forceinline__ void pipePre(
    u16* ringb,
    const u16* const (&Ahi)[NA], const u16* const (&Alo)[NA],
    const u16* const (&Wjb)[NS], const int (&ai)[NS],
    f32x4* (&acc)[NS][3],   // acc[s] = {R,Z,N}, each -> f32x4[2] (fc)
    int row0w, int lane, int wave) {
  constexpr int B = NS * 3 + 2 * NA;
  constexpr int A2 = 2 * NA;
  constexpr int SLOT = NS * 6144;
  const int quad = lane >> 4, n16 = lane & 15;
  // kc-blocked A base: rowtile + rr=n16*32 + cc=quad*8; step 512 u16 per kc.
  const u16* aH[NA]; const u16* aL[NA];
#pragma unroll
  for (int n = 0; n < NA; ++n) {
    const size_t base = (size_t)(row0w >> 4) * (KC_H * 512) + n16 * 32 + quad * 8;
    aH[n] = Ahi[n] + base;
    aL[n] = Alo[n] + base;
  }
  const u16* srcB[NS * 3]; int dstO[NS * 3];
  piece_map<NS>(Wjb, lane, wave, srcB, dstO);
  u16* pb[3] = {ringb, ringb + SLOT, ringb + 2 * SLOT};
  AFN<NA> af0, af1, af2;

  auto issueA = [&](int ikc, AFN<NA>& dst) {
#pragma unroll
    for (int n = 0; n < NA; ++n) {
      dst.h[n] = load_a16<LOC>(aH[n] + ikc * 512);
      dst.l[n] = load_a16<LOC>(aL[n] + ikc * 512);
    }
  };
  auto issueB = [&](int ikc, int si, AFN<NA>& dst) {
#pragma unroll
    for (int i = 0; i < NS * 3; ++i)
      __builtin_amdgcn_global_load_lds(
          (const glb_u32*)(srcB[i] + (size_t)ikc * 6144),
          (lds_u32*)(pb[si] + dstO[i]), 16, 0, 0);
    issueA(ikc, dst);
  };
  auto cons = [&](int si, AFN<NA>& a) {
    fence_afn(a);
#pragma unroll
    for (int s = 0; s < NS; ++s)
#pragma unroll
      for (int f = 0; f < 2; ++f)
        mfma_kc9((const lds_u16*)(pb[si] + s * 6144 + f * 3072), lane,
                 a.h[ai[s]], a.l[ai[s]],
                 acc[s][0][f], acc[s][1][f], acc[s][2][f]);
  };

  WAIT_VM(0);  // drain own prefetch DMAs (slots 0,1 weights)
  issueA(0, af0);
  issueA(1, af1);
  wvm<A2>(); bar_raw(); issueB(2, 2, af2); cons(0, af0);   // kc=0
  wvm<B>();  bar_raw(); issueB(3, 0, af0); cons(1, af1);   // kc=1
#pragma unroll 1
  for (int q = 0; q < 4; ++q) {  // covers kc 2..13
    const int base = 4 + q * 3;  // ikc of first issue
    wvm<B>(); bar_raw(); issueB(base + 0, 1, af1); cons(2, af2);
    wvm<B>(); bar_raw(); issueB(base + 1, 2, af2); cons(0, af0);
    wvm<B>(); bar_raw(); issueB(base + 2, 0, af0); cons(1, af1);
  }
  wvm<B>(); bar_raw(); cons(2, af2);   // kc=14
  wvm<0>(); bar_raw(); cons(0, af0);   // kc=15
}

// x-accumulate for encoder L0 (barrier shadow; normal cached reads).
__device__ __forceinline__ void x_acc(const float* x, int t, const u16* Wp,
                                      int jb, int row0w, int lane,
                                      f32x4* aR, f32x4* aZ, f32x4* aN) {
  const int quad = lane >> 4, n16 = lane & 15;
  const float* xp = x + (size_t)(row0w + n16) * (TT * DIN) +
                    (size_t)t * DIN + quad * 8;
  f32x4 v0 = *(const f32x4*)xp;
  f32x4 v1 = *(const f32x4*)(xp + 4);
  bf16x8 hi, lo;
#pragma unroll
  for (int i = 0; i < 8; ++i) {
    float f = (i < 4) ? v0[i] : v1[i - 4];
    u16 h = (u16)(__float_as_uint(f) >> 16);
    hi[i] = (short)h;
    lo[i] = (short)f2bf_rne(f - bf2f(h));
  }
#pragma unroll
  for (int f = 0; f < 2; ++f)
    mfma_kc9_g(Wp + ((size_t)jb * 2 + f) * 3072, lane, hi, lo,
               aR[f], aZ[f], aN[f]);
}

// Row-group barrier, split arrive/wait (window filled with prefetch/x-phase).
__device__ __forceinline__ void gbar_arrive(unsigned* gen) {
  WAIT_VM(0);  // all this wave's h-stores retired (to L2 if local, LLC if not)
  __syncthreads();
  if (threadIdx.x == 0) atomicAdd(gen, 1u);  // device-scope
}
__device__ __forceinline__ void gbar_wait(unsigned* gen, unsigned target) {
  if (threadIdx.x == 0) {
    while (load_sc_u32w(gen) < target) __builtin_amdgcn_s_sleep(2);
  }
  __syncthreads();
}

// GRU epilogue with register-resident own-tile h; kc-blocked store layout.
__device__ __forceinline__ void gru_epi_reg(
    const float* bi, const float* bh, float (*ht)[4],
    u16* hnH, u16* hnL, int jb, int col0, int row0w, int quad, int n16,
    bool loc,
    const f32x4* aR, const f32x4* aZ, const f32x4* aNX, const f32x4* aNH) {
  const size_t hb = ((size_t)(row0w >> 4) * KC_H + jb) * 512;
#pragma unroll
  for (int f = 0; f < 2; ++f) {
    const int col = col0 + f * 16;
    const float bir = bi[col],          bhr = bh[col];
    const float biz = bi[HD + col],     bhz = bh[HD + col];
    const float bin = bi[2 * HD + col], bhn = bh[2 * HD + col];
#pragma unroll
    for (int r = 0; r < 4; ++r) {
      const size_t idx = hb + (quad * 4 + r) * 32 + f * 16 + n16;
      float rr = sigm(aR[f][r] + bir + bhr);
      float zz = sigm(aZ[f][r] + biz + bhz);
      float nn = tanh_(aNX[f][r] + bin + rr * (aNH[f][r] + bhn));
      float hv = (1.f - zz) * nn + zz * ht[f][r];
      ht[f][r] = hv;
      store_h_sc(hnH, hnL, idx, hv, loc);
    }
  }
}

__global__ __launch_bounds__(256, 1)
void gru_persistent_kernel(
    const float* x,
    const u16* pkX0, const u16* pkH0, const float* bi0, const float* bh0,
    const u16* pkX1, const u16* pkH1, const float* bi1, const float* bh1,
    const u16* pkD0H, const float* dbi0, const float* dbh0, const float* dW0,
    const u16* pkD1I, const u16* pkD1H, const float* dbi1, const float* dbh1,
    const float* outW, const float* outb, const float* dstart,
    u16* h1aH, u16* h1aL, u16* h1bH, u16* h1bL,
    u16* h2aH, u16* h2aL, u16* h2bH, u16* h2bL,
    float* yfull, float* dout, unsigned* gen,
    unsigned* ictr, unsigned* xclaim, unsigned* taken, unsigned* gmask) {
  __shared__ u16 ring[3 * 3 * 6144];  // 108 KB: 3-slot triple-stream ring
  __shared__ int meta[4];
  const int tid = threadIdx.x, wave = tid >> 6, lane = tid & 63;
  const int quad = lane >> 4, n16 = lane & 15;

  // ---- XCD-aware role claiming (correct under ANY block->XCD mapping) ----
  // XCD x owns row groups {2x, 2x+1} x 16 jb (rowg-major: h-locality).
  // Overflow blocks claim leftover roles; any group not fully on one XCD
  // falls back to LLC-coherent h (bit-identical results).
  if (tid == 0) {
    unsigned xcd;
    asm volatile("s_getreg_b32 %0, hwreg(HW_REG_XCC_ID)" : "=s"(xcd));
    xcd &= 7;
    unsigned s = atomicAdd(xclaim + xcd * 64, 1u);
    int role = -1;
    if (s < 32) {
      role = (int)(((2u * xcd + (s >> 4)) << 4) | (s & 15u));
      atomicExch(taken + role, 1u);
      atomicOr(gmask + (role >> 4) * 64, 1u << xcd);
    }
    atomicAdd(ictr, 1u);
    while (load_sc_u32w(ictr) < NBLK) __builtin_amdgcn_s_sleep(2);
    if (role < 0) {
      int r = 0;
      for (;;) {
        if (load_sc_u32w(taken + r) == 0u &&
            atomicCAS(taken + r, 0u, 1u) == 0u) { role = r; break; }
        r = (r + 1) & 255;
      }
      atomicOr(gmask + (role >> 4) * 64, 0x100u);
    }
    atomicAdd(ictr, 1u);
    while (load_sc_u32w(ictr) < 2 * NBLK) __builtin_amdgcn_s_sleep(2);
    unsigned m = load_sc_u32w(gmask + (role >> 4) * 64);
    meta[2] = role;
    meta[3] = (__popc(m & 0xFFu) == 1 && !(m & 0x100u)) ? 1 : 0;
  }
  __syncthreads();
  const int role = meta[2];
  const bool loc = meta[3] != 0;
  const int jb = role & 15;
  const int row0 = (role >> 4) * 64;
  const int row0w = row0 + wave * 16;  // 4 waves = 4 row sub-tiles
  const int col0 = jb * 32 + n16;
  u16* ringb = &ring[0];
  const f32x4 z4 = {0.f, 0.f, 0.f, 0.f};
  const size_t jbs = (size_t)jb * (KC_H * 2 * 3072);  // jb slice base (K=512)
  const u16* pkH0j = pkH0 + jbs;
  const u16* pkX1j = pkX1 + jbs;
  const u16* pkH1j = pkH1 + jbs;
  const u16* pkD0Hj = pkD0H + jbs;
  const u16* pkD1Ij = pkD1I + jbs;
  const u16* pkD1Hj = pkD1H + jbs;
  unsigned* geng = gen + (role >> 4) * 64;  // per-row-group counter

  u16 *h1cH = h1aH, *h1cL = h1aL, *h1nH = h1bH, *h1nL = h1bL;
  u16 *h2cH = h2aH, *h2cL = h2aL, *h2nH = h2bH, *h2nL = h2bL;
  float ht1[2][4] = {{0, 0, 0, 0}, {0, 0, 0, 0}};  // own h1 tile (fc, r)
  float ht2[2][4] = {{0, 0, 0, 0}, {0, 0, 0, 0}};  // own h2 tile (fc, r)
  unsigned it = 0;

  // x-phase accumulators for the upcoming encoder step (barrier-shadow).
  f32x4 xR[2] = {z4, z4}, xZ[2] = {z4, z4}, xN[2] = {z4, z4};
  {  // initial prefetch for k=0 single pipe + x-acc(0)
    const u16* Wv1[1] = {pkH0j};
    stageW2<1>(ringb, Wv1, lane, wave);
    x_acc(x, 0, pkX0, jb, row0w, lane, xR, xZ, xN);
  }

  // ---- encoder: 513 skewed phases; ONE merged pipe per step ----
  for (int k = 0; k <= TT; ++k) {
    f32x4 R0[2], Z0[2], NX0[2], NH0[2] = {z4, z4};
    f32x4 R1[2] = {z4, z4}, Z1[2] = {z4, z4}, NX1[2] = {z4, z4}, NH1[2] = {z4, z4};
    if (k < TT) {
      R0[0] = xR[0]; R0[1] = xR[1];
      Z0[0] = xZ[0]; Z0[1] = xZ[1];
      NX0[0] = xN[0]; NX0[1] = xN[1];
    } else {
      R0[0] = z4; R0[1] = z4; Z0[0] = z4; Z0[1] = z4; NX0[0] = z4; NX0[1] = z4;
    }
    if (k > 0 && k < TT) {
      // Triple: L0-h (pkH0*h1), L1-x (pkX1*h1), L1-h (pkH1*h2).
      const u16* Ah[2] = {h1cH, h2cH};
      const u16* Al[2] = {h1cL, h2cL};
      const u16* Wv[3] = {pkH0j, pkX1j, pkH1j};
      const int ai3[3] = {0, 0, 1};
      f32x4* ac[3][3] = {{R0, Z0, NH0}, {R1, Z1, NX1}, {R1, Z1, NH1}};
      if (loc) pipePre<3, 2, true>(ringb, Ah, Al, Wv, ai3, ac, row0w, lane, wave);
      else     pipePre<3, 2, false>(ringb, Ah, Al, Wv, ai3, ac, row0w, lane, wave);
    } else if (k == 0) {
      const u16* Ah[1] = {h1cH};
      const u16* Al[1] = {h1cL};
      const u16* Wv[1] = {pkH0j};
      const int ai1[1] = {0};
      f32x4* ac[1][3] = {{R0, Z0, NH0}};
      if (loc) pipePre<1, 1, true>(ringb, Ah, Al, Wv, ai1, ac, row0w, lane, wave);
      else     pipePre<1, 1, false>(ringb, Ah, Al, Wv, ai1, ac, row0w, lane, wave);
    } else {  // k == TT: L1-x + L1-h only
      const u16* Ah[2] = {h1cH, h2cH};
      const u16* Al[2] = {h1cL, h2cL};
      const u16* Wv[2] = {pkX1j, pkH1j};
      const int ai2[2] = {0, 1};
      f32x4* ac[2][3] = {{R1, Z1, NX1}, {R1, Z1, NH1}};
      if (loc) pipePre<2, 2, true>(ringb, Ah, Al, Wv, ai2, ac, row0w, lane, wave);
      else     pipePre<2, 2, false>(ringb, Ah, Al, Wv, ai2, ac, row0w, lane, wave);
    }
    if (k < TT)
      gru_epi_reg(bi0, bh0, ht1, h1nH, h1nL, jb, col0, row0w, quad, n16, loc,
                  R0, Z0, NX0, NH0);
    if (k > 0)
      gru_epi_reg(bi1, bh1, ht2, h2nH, h2nL, jb, col0, row0w, quad, n16, loc,
                  R1, Z1, NX1, NH1);
    ++it;
    gbar_arrive(geng);
    // ---- barrier shadow: peer-independent work ----
    if (k + 1 < TT) {
      xR[0] = z4; xR[1] = z4; xZ[0] = z4; xZ[1] = z4; xN[0] = z4; xN[1] = z4;
      x_acc(x, k + 1, pkX0, jb, row0w, lane, xR, xZ, xN);
    }
    if (k + 1 < TT) {
      const u16* Wv3[3] = {pkH0j, pkX1j, pkH1j};
      stageW2<3>(ringb, Wv3, lane, wave);
    } else if (k + 1 == TT) {
      const u16* Wv2[2] = {pkX1j, pkH1j};
      stageW2<2>(ringb, Wv2, lane, wave);
    } else {  // k == TT -> next is decoder L0 (single)
      const u16* Wv1[1] = {pkD0Hj};
      stageW2<1>(ringb, Wv1, lane, wave);
    }
    gbar_wait(geng, GRPB * it);
    if (k < TT) { u16* t0 = h1cH; h1cH = h1nH; h1nH = t0;
                  u16* t1 = h1cL; h1cL = h1nL; h1nL = t1; }
    if (k > 0)  { u16* t0 = h2cH; h2cH = h2nH; h2nH = t0;
                  u16* t1 = h2cL; h2cL = h2nL; h2nL = t1; }
  }

  // ---- decoder: 96 steps x (L0, L1); y via atomics into yfull[2][BB] ----
  for (int t = 0; t < PP; ++t) {
    {  // dec L0
      f32x4 R[2] = {z4, z4}, Z[2] = {z4, z4}, NH[2] = {z4, z4};
      {
        const u16* Ah[1] = {h1cH};
        const u16* Al[1] = {h1cL};
        const u16* Wv[1] = {pkD0Hj};
        const int ai1[1] = {0};
        f32x4* ac[1][3] = {{R, Z, NH}};
        if (loc) pipePre<1, 1, true>(ringb, Ah, Al, Wv, ai1, ac, row0w, lane, wave);
        else     pipePre<1, 1, false>(ringb, Ah, Al, Wv, ai1, ac, row0w, lane, wave);
      }
      float yl[4] = {0, 0, 0, 0};
      if (t > 0) {
        const float* yb = yfull + ((t - 1) & 1) * BB;
#pragma unroll
        for (int r = 0; r < 4; ++r) {
          const float* p = yb + (row0w + quad * 4 + r);
          asm volatile("global_load_dword %0, %1, off sc0 sc1"
                       : "=&v"(yl[r]) : "v"(p) : "memory");
        }
        WAIT_VM(0);
#pragma unroll
        for (int r = 0; r < 4; ++r)
          asm volatile("" : "+v"(yl[r]));
      }
      const float ds0 = dstart[0], ob0 = outb[0];
      const size_t hb = ((size_t)(row0w >> 4) * KC_H + jb) * 512;
#pragma unroll
      for (int f = 0; f < 2; ++f) {
        const int col = col0 + f * 16;
        const float bir = dbi0[col],          bhr = dbh0[col];
        const float biz = dbi0[HD + col],     bhz = dbh0[HD + col];
        const float bin = dbi0[2 * HD + col], bhn = dbh0[2 * HD + col];
        const float w0r = dW0[col], w0z = dW0[HD + col], w0n = dW0[2 * HD + col];
#pragma unroll
        for (int r = 0; r < 4; ++r) {
          const int row = row0w + quad * 4 + r;
          const size_t idx = hb + (quad * 4 + r) * 32 + f * 16 + n16;
          float yv = (t == 0) ? ds0 : (ob0 + yl[r]);
          if (f == 0 && t > 0 && jb == 0 && n16 == 0)
            dout[(size_t)row * PP + (t - 1)] = yv;
          float rr = sigm(R[f][r] + bir + bhr + yv * w0r);
          float zz = sigm(Z[f][r] + biz + bhz + yv * w0z);
          float nn = tanh_(bin + yv * w0n + rr * (NH[f][r] + bhn));
          float hv = (1.f - zz) * nn + zz * ht1[f][r];
          ht1[f][r] = hv;
          store_h_sc(h1nH, h1nL, idx, hv, loc);
        }
      }
    }
    ++it;
    gbar_arrive(geng);
    {  // barrier shadow: prefetch dual {D1I, D1H}
      const u16* Wv2[2] = {pkD1Ij, pkD1Hj};
      stageW2<2>(ringb, Wv2, lane, wave);
    }
    gbar_wait(geng, GRPB * it);
    {  // dec L1: merged dual pipe (pkD1I*h1n + pkD1H*h2c)
      f32x4 R[2] = {z4, z4}, Z[2] = {z4, z4}, NX[2] = {z4, z4}, NH[2] = {z4, z4};
      {
        const u16* Ah[2] = {h1nH, h2cH};
        const u16* Al[2] = {h1nL, h2cL};
        const u16* Wv[2] = {pkD1Ij, pkD1Hj};
        const int ai2[2] = {0, 1};
        f32x4* ac[2][3] = {{R, Z, NX}, {R, Z, NH}};
        if (loc) pipePre<2, 2, true>(ringb, Ah, Al, Wv, ai2, ac, row0w, lane, wave);
        else     pipePre<2, 2, false>(ringb, Ah, Al, Wv, ai2, ac, row0w, lane, wave);
      }
      float vs[4] = {0, 0, 0, 0};
      const size_t hb = ((size_t)(row0w >> 4) * KC_H + jb) * 512;
#pragma unroll
      for (int f = 0; f < 2; ++f) {
        const int col = col0 + f * 16;
        const float bir = dbi1[col],          bhr = dbh1[col];
        const float biz = dbi1[HD + col],     bhz = dbh1[HD + col];
        const float bin = dbi1[2 * HD + col], bhn = dbh1[2 * HD + col];
        const float wo = outW[col];
#pragma unroll
        for (int r = 0; r < 4; ++r) {
          const size_t idx = hb + (quad * 4 + r) * 32 + f * 16 + n16;
          float rr = sigm(R[f][r] + bir + bhr);
          float zz = sigm(Z[f][r] + biz + bhz);
          float nn = tanh_(NX[f][r] + bin + rr * (NH[f][r] + bhn));
          float hv = (1.f - zz) * nn + zz * ht2[f][r];
          ht2[f][r] = hv;
          store_h_sc(h2nH, h2nL, idx, hv, loc);
          float v = hv * wo;
#pragma unroll
          for (int off = 1; off < 16; off <<= 1) v += __shfl_xor(v, off, 16);
          vs[r] += v;
        }
      }
      float* yw = yfull + (t & 1) * BB;
      float* yz = yfull + ((t - 1) & 1) * BB;
#pragma unroll
      for (int r = 0; r < 4; ++r) {
        const int row = row0w + quad * 4 + r;
        if (n16 == 0) {
          atomicAdd(yw + row, vs[r]);
          // zero last parity (read by dec L0 this iter; rewritten at t+1)
          if (t > 0 && jb == 0) store_sc_f32(yz + row, 0.f);
        }
      }
    }
    ++it;
    gbar_arrive(geng);
    if (t + 1 < PP) {  // barrier shadow: prefetch next dec L0 single
      const u16* Wv1[1] = {pkD0Hj};
      stageW2<1>(ringb, Wv1, lane, wave);
    }
    gbar_wait(geng, GRPB * it);
    { u16* t0 = h1cH; h1cH = h1nH; h1nH = t0;
      u16* t1 = h1cL; h1cL = h1nL; h1nL = t1; }
    { u16* t0 = h2cH; h2cH = h2nH; h2nH = t0;
      u16* t1 = h2cL; h2cL = h2nL; h2nL = t1; }
  }

  // ---- finalize: y(P-1), group-local (jb==0 block owns its 64 rows) ----
  if (jb == 0 && tid < 64) {
    int row = row0 + tid;
    float v = load_sc_f32w(yfull + ((PP - 1) & 1) * BB + row);
    dout[(size_t)row * PP + (PP - 1)] = outb[0] + v;
  }
}

extern "C" void kernel_launch(void* const* d_in, const int* in_sizes, int n_in,
                              void* d_out, int out_size, void* d_ws, size_t ws_size,
                              hipStream_t stream) {
  const float* x      = (const float*)d_in[0];
  const float* eW_ih0 = (const float*)d_in[1];
  const float* eW_hh0 = (const float*)d_in[2];
  const float* eb_ih0 = (const float*)d_in[3];
  const float* eb_hh0 = (const float*)d_in[4];
  const float* eW_ih1 = (const float*)d_in[5];
  const float* eW_hh1 = (const float*)d_in[6];
  const float* eb_ih1 = (const float*)d_in[7];
  const float* eb_hh1 = (const float*)d_in[8];
  const float* dW_ih0 = (const float*)d_in[9];
  const float* dW_hh0 = (const float*)d_in[10];
  const float* db_ih0 = (const float*)d_in[11];
  const float* db_hh0 = (const float*)d_in[12];
  const float* dW_ih1 = (const float*)d_in[13];
  const float* dW_hh1 = (const float*)d_in[14];
  const float* db_ih1 = (const float*)d_in[15];
  const float* db_hh1 = (const float*)d_in[16];
  const float* outW   = (const float*)d_in[17];
  const float* outb   = (const float*)d_in[18];
  const float* dstart = (const float*)d_in[19];
  float* out = (float*)d_out;

  char* w = (char*)d_ws;
  size_t off = 0;
  auto carve = [&](size_t bytes) -> void* {
    void* p = w + off;
    off = (off + bytes + 255) & ~(size_t)255;
    return p;
  };
  u16* h1aH = (u16*)carve((size_t)BB * HD * 2); u16* h1aL = (u16*)carve((size_t)BB * HD * 2);
  u16* h1bH = (u16*)carve((size_t)BB * HD * 2); u16* h1bL = (u16*)carve((size_t)BB * HD * 2);
  u16* h2aH = (u16*)carve((size_t)BB * HD * 2); u16* h2aL = (u16*)carve((size_t)BB * HD * 2);
  u16* h2bH = (u16*)carve((size_t)BB * HD * 2); u16* h2bL = (u16*)carve((size_t)BB * HD * 2);
  float* yfull = (float*)carve((size_t)2 * BB * 4);
  unsigned* gen = (unsigned*)carve(4096);     // 16 group counters, 256-B stride
  unsigned* ictr = (unsigned*)carve(256);     // init full-grid counter
  unsigned* xclaim = (unsigned*)carve(2048);  // 8 per-XCD claim ctrs, 256-B
  unsigned* taken = (unsigned*)carve(1024);   // 256 role flags
  unsigned* gmask = (unsigned*)carve(4096);   // 16 group XCD masks, 256-B
  auto carve_pack = [&](int K) -> u16* {
    return (u16*)carve((size_t)3 * HD * K * 2 * 2);
  };
  u16* pk_e0ih = carve_pack(DIN);
  u16* pk_e0hh = carve_pack(HD);
  u16* pk_e1ih = carve_pack(HD);
  u16* pk_e1hh = carve_pack(HD);
  u16* pk_d0hh = carve_pack(HD);
  u16* pk_d1ih = carve_pack(HD);
  u16* pk_d1hh = carve_pack(HD);

  hipMemsetAsync(h1aH, 0, (size_t)BB * HD * 2, stream);
  hipMemsetAsync(h1aL, 0, (size_t)BB * HD * 2, stream);
  hipMemsetAsync(h2aH, 0, (size_t)BB * HD * 2, stream);
  hipMemsetAsync(h2aL, 0, (size_t)BB * HD * 2, stream);
  hipMemsetAsync(yfull, 0, (size_t)2 * BB * 4, stream);
  hipMemsetAsync(gen, 0, 4096, stream);
  hipMemsetAsync(ictr, 0, 256, stream);
  hipMemsetAsync(xclaim, 0, 2048, stream);
  hipMemsetAsync(taken, 0, 1024, stream);
  hipMemsetAsync(gmask, 0, 4096, stream);

  auto pack = [&](const float* W, int K, u16* dst) {
    int total = 16 * (K >> 5) * 2 * 6 * 64;
    pack_w_kernel<<<(total + 255) / 256, 256, 0, stream>>>(W, K, dst);
  };
  pack(eW_ih0, DIN, pk_e0ih);
  pack(eW_hh0, HD, pk_e0hh);
  pack(eW_ih1, HD, pk_e1ih);
  pack(eW_hh1, HD, pk_e1hh);
  pack(dW_hh0, HD, pk_d0hh);
  pack(dW_ih1, HD, pk_d1ih);
  pack(dW_hh1, HD, pk_d1hh);

  gru_persistent_kernel<<<NBLK, 256, 0, stream>>>(
      x, pk_e0ih, pk_e0hh, eb_ih0, eb_hh0,
      pk_e1ih, pk_e1hh, eb_ih1, eb_hh1,
      pk_d0hh, db_ih0, db_hh0, dW_ih0,
      pk_d1ih, pk_d1hh, db_ih1, db_hh1,
      outW, outb, dstart,
      h1aH, h1aL, h1bH, h1bL, h2aH, h2aL, h2bH, h2bL,
      yfull, out, gen, ictr, xclaim, taken, gmask);
}

// Round 10
// 15864.723 us; speedup vs baseline: 1.3013x; 1.3013x over previous
//
#include <hip/hip_runtime.h>

#define HD 512
#define BB 1024
#define TT 512
#define PP 96
#define DIN 32
#define KC_H 16
#define NBLK 256
#define GRPB 16  // blocks per row-group barrier (all 16 jb of one row group)

typedef unsigned short u16;
typedef __attribute__((ext_vector_type(8))) short bf16x8;
typedef __attribute__((ext_vector_type(4))) float f32x4;
typedef __attribute__((ext_vector_type(4))) unsigned u32x4;
typedef __attribute__((address_space(3))) unsigned int lds_u32;
typedef __attribute__((address_space(3))) u16 lds_u16;
typedef __attribute__((address_space(1))) unsigned int glb_u32;

#define WAIT_VM(N) asm volatile("s_waitcnt vmcnt(" #N ")" ::: "memory")
__device__ __forceinline__ void bar_raw() { asm volatile("s_barrier" ::: "memory"); }

template <int N> __device__ __forceinline__ void wvm() {
  if constexpr (N == 0) WAIT_VM(0);
  else if constexpr (N == 2) WAIT_VM(2);
  else if constexpr (N == 4) WAIT_VM(4);
  else if constexpr (N == 5) WAIT_VM(5);
  else if constexpr (N == 10) WAIT_VM(10);
  else if constexpr (N == 13) WAIT_VM(13);
}

__device__ __forceinline__ float bf2f(u16 s) {
  return __uint_as_float(((unsigned)s) << 16);
}
__device__ __forceinline__ u16 f2bf_rne(float f) {
  unsigned u = __float_as_uint(f);
  u += 0x7FFF + ((u >> 16) & 1);
  return (u16)(u >> 16);
}
__device__ __forceinline__ float sigm(float v) { return 1.f / (1.f + __expf(-v)); }
__device__ __forceinline__ float tanh_(float a) {
  return 1.f - 2.f / (__expf(2.f * a) + 1.f);
}

// ---- coherent (LLC-point, L2-bypass) access helpers: sc0 sc1 ----
__device__ __forceinline__ u32x4 load_au4(const unsigned* p) {
  u32x4 r;
  asm volatile("global_load_dwordx4 %0, %1, off sc0 sc1" : "=&v"(r) : "v"(p) : "memory");
  return r;
}
__device__ __forceinline__ void store_sc_u32(unsigned* p, unsigned v) {
  asm volatile("global_store_dword %0, %1, off sc0 sc1" :: "v"(p), "v"(v) : "memory");
}
__device__ __forceinline__ void store_sc_f32(float* p, float v) {
  asm volatile("global_store_dword %0, %1, off sc0 sc1" :: "v"(p), "v"(v) : "memory");
}
__device__ __forceinline__ float load_sc_f32w(const float* p) {  // load + full wait
  float v;
  asm volatile("global_load_dword %0, %1, off sc0 sc1\ns_waitcnt vmcnt(0)"
               : "=&v"(v) : "v"(p) : "memory");
  return v;
}
__device__ __forceinline__ unsigned load_sc_u32w(const unsigned* p) {
  unsigned v;
  asm volatile("global_load_dword %0, %1, off sc0 sc1\ns_waitcnt vmcnt(0)"
               : "=&v"(v) : "v"(p) : "memory");
  return v;
}
// h element = ONE u32: lo16 = bf16 hi (trunc), hi16 = bf16 residual (rne).
// Replaces two 2-byte coherent stores with one dword store (halves the
// coherent store-transaction stream; removes all sub-dword writes).
__device__ __forceinline__ void store_h32(unsigned* H, size_t idx, float hv) {
  unsigned hi = __float_as_uint(hv) >> 16;  // trunc; lo corrects
  unsigned lo = (unsigned)f2bf_rne(hv - bf2f((u16)hi));
  store_sc_u32(H + idx, hi | (lo << 16));
}

// ---- h-state layout: kc-blocked tiles (as R8), u32 elements ----
// h[rowtile:64][kc:16][rr:16][cc:32] u32; element (row,col) at
// (row>>4)*8192 + (col>>5)*512 + (row&15)*32 + (col&31).

// Pack fp32 weight W[3H x K] into fc-contiguous MFMA B-frag bf16 hi/lo layout.
__global__ void pack_w_kernel(const float* __restrict__ W, int K,
                              u16* __restrict__ out) {
  int tid = blockIdx.x * 256 + threadIdx.x;
  int KC = K >> 5;
  int total = 16 * KC * 2 * 6 * 64;
  if (tid >= total) return;
  int lane = tid & 63;
  int rest = tid >> 6;
  int gs = rest % 6; rest /= 6;
  int fc = rest & 1; rest >>= 1;
  int kc = rest % KC;
  int jb = rest / KC;
  int g = gs >> 1, s = gs & 1;
  int j = jb * 32 + fc * 16 + (lane & 15);
  int k = kc * 32 + (lane >> 4) * 8;
  const float* src = W + (size_t)(g * HD + j) * K + k;
  bf16x8 v;
#pragma unroll
  for (int i = 0; i < 8; ++i) {
    float f = src[i];
    u16 hi = f2bf_rne(f);
    v[i] = (short)((s == 0) ? hi : f2bf_rne(f - bf2f(hi)));
  }
  *(bf16x8*)(out + (size_t)tid * 8) = v;
}

// A fragments: NA streams x 8 packed u32 (two dwordx4 loads per stream).
template <int NA> struct AFN { u32x4 w0[NA]; u32x4 w1[NA]; };
template <int NA>
__device__ __forceinline__ void fence_afn(AFN<NA>& a) {
#pragma unroll
  for (int n = 0; n < NA; ++n)
    asm volatile("" : "+v"(a.w0[n]), "+v"(a.w1[n]));
}
__device__ __forceinline__ void unpack_hl(u32x4 w0, u32x4 w1,
                                          bf16x8& hi, bf16x8& lo) {
#pragma unroll
  for (int i = 0; i < 4; ++i) {
    unsigned a = w0[i], b = w1[i];
    hi[i] = (short)(u16)(a & 0xffffu);
    lo[i] = (short)(u16)(a >> 16);
    hi[i + 4] = (short)(u16)(b & 0xffffu);
    lo[i + 4] = (short)(u16)(b >> 16);
  }
}

// 9 MFMAs for one (stream, fc) 6KB chunk (6 frag groups of 512 u16).
__device__ __forceinline__ void mfma_kc9(const lds_u16* base, int lane,
                                         bf16x8 ah, bf16x8 al,
                                         f32x4& R, f32x4& Z, f32x4& N) {
  typedef __attribute__((address_space(3))) const bf16x8 lds_bf16x8;
  const lds_u16* p = base + lane * 8;
#pragma unroll
  for (int g = 0; g < 3; ++g) {
    f32x4* a = (g == 0) ? &R : (g == 1) ? &Z : &N;
    bf16x8 whi = *(lds_bf16x8*)(p + (g * 2 + 0) * 512);
    bf16x8 wlo = *(lds_bf16x8*)(p + (g * 2 + 1) * 512);
    *a = __builtin_amdgcn_mfma_f32_16x16x32_bf16(ah, whi, *a, 0, 0, 0);
    *a = __builtin_amdgcn_mfma_f32_16x16x32_bf16(al, whi, *a, 0, 0, 0);
    *a = __builtin_amdgcn_mfma_f32_16x16x32_bf16(ah, wlo, *a, 0, 0, 0);
  }
}
// Global variant for the K=32 x-phase (L2-hot, compiler-managed waits).
__device__ __forceinline__ void mfma_kc9_g(const u16* base, int lane,
                                           bf16x8 ah, bf16x8 al,
                                           f32x4& R, f32x4& Z, f32x4& N) {
  const u16* p = base + lane * 8;
#pragma unroll
  for (int g = 0; g < 3; ++g) {
    f32x4* a = (g == 0) ? &R : (g == 1) ? &Z : &N;
    bf16x8 whi = *(const bf16x8*)(p + (g * 2 + 0) * 512);
    bf16x8 wlo = *(const bf16x8*)(p + (g * 2 + 1) * 512);
    *a = __builtin_amdgcn_mfma_f32_16x16x32_bf16(ah, whi, *a, 0, 0, 0);
    *a = __builtin_amdgcn_mfma_f32_16x16x32_bf16(al, whi, *a, 0, 0, 0);
    *a = __builtin_amdgcn_mfma_f32_16x16x32_bf16(ah, wlo, *a, 0, 0, 0);
  }
}

// Weight-piece mapping: NS streams x 12 x 1KB pieces; each wave stages NS*3.
template <int NS>
__device__ __forceinline__ void piece_map(const u16* const (&Wjb)[NS],
                                          int lane, int wave,
                                          const u16* (&srcB)[NS * 3],
                                          int (&dstO)[NS * 3]) {
#pragma unroll
  for (int i = 0; i < NS * 3; ++i) {
    const int p = wave * (NS * 3) + i;
    const int s = p / 12, r = p % 12, f2 = r / 6, j = r % 6;
    const int co = f2 * 3072 + j * 512;
    srcB[i] = Wjb[s] + co + lane * 8;
    dstO[i] = s * 6144 + co;
  }
}

// Barrier-shadow weight prefetch for slots 0,1 (weights read-only -> legal
// before the row-group barrier completes).
template <int NS>
__device__ __forceinline__ void stageW2(u16* ringb, const u16* const (&Wjb)[NS],
                                        int lane, int wave) {
  const u16* srcB[NS * 3]; int dstO[NS * 3];
  piece_map<NS>(Wjb, lane, wave, srcB, dstO);
#pragma unroll
  for (int ikc = 0; ikc < 2; ++ikc)
#pragma unroll
    for (int i = 0; i < NS * 3; ++i)
      __builtin_amdgcn_global_load_lds(
          (const glb_u32*)(srcB[i] + (size_t)ikc * 6144),
          (lds_u32*)(ringb + (size_t)ikc * NS * 6144 + dstO[i]), 16, 0, 0);
}

// Multi-stream K=512 GEMM pipe, depth-3 ring, PREFETCHED slots 0,1.
// Steady state bundle = NS*3 weight DMAs + 2*NA packed-A dwordx4 loads.
template <int NS, int NA>
__device__ __forceinline__ void pipePre(
    u16* ringb,
    const unsigned* const (&Ahl)[NA],
    const u16* const (&Wjb)[NS], const int (&ai)[NS],
    f32x4* (&acc)[NS][3],   // acc[s] = {R,Z,N}, each -> f32x4[2] (fc)
    int row0w, int lane, int wave) {
  constexpr int B = NS * 3 + 2 * NA;
  constexpr int A2 = 2 * NA;
  constexpr int SLOT = NS * 6144;
  const int quad = lane >> 4, n16 = lane & 15;
  // kc-blocked A base (u32 units): rowtile + rr=n16*32 + cc=quad*8.
  const unsigned* aW[NA];
#pragma unroll
  for (int n = 0; n < NA; ++n)
    aW[n] = Ahl[n] + (size_t)(row0w >> 4) * (KC_H * 512) + n16 * 32 + quad * 8;
  const u16* srcB[NS * 3]; int dstO[NS * 3];
  piece_map<NS>(Wjb, lane, wave, srcB, dstO);
  u16* pb[3] = {ringb, ringb + SLOT, ringb + 2 * SLOT};
  AFN<NA> af0, af1, af2;

  auto issueA = [&](int ikc, AFN<NA>& dst) {
#pragma unroll
    for (int n = 0; n < NA; ++n) {
      dst.w0[n] = load_au4(aW[n] + ikc * 512);
      dst.w1[n] = load_au4(aW[n] + ikc * 512 + 4);
    }
  };
  auto issueB = [&](int ikc, int si, AFN<NA>& dst) {
#pragma unroll
    for (int i = 0; i < NS * 3; ++i)
      __builtin_amdgcn_global_load_lds(
          (const glb_u32*)(srcB[i] + (size_t)ikc * 6144),
          (lds_u32*)(pb[si] + dstO[i]), 16, 0, 0);
    issueA(ikc, dst);
  };
  auto cons = [&](int si, AFN<NA>& a) {
    fence_afn(a);
    bf16x8 hi[NA], lo[NA];
#pragma unroll
    for (int n = 0; n < NA; ++n)
      unpack_hl(a.w0[n], a.w1[n], hi[n], lo[n]);
#pragma unroll
    for (int s = 0; s < NS; ++s)
#pragma unroll
      for (int f = 0; f < 2; ++f)
        mfma_kc9((const lds_u16*)(pb[si] + s * 6144 + f * 3072), lane,
                 hi[ai[s]], lo[ai[s]],
                 acc[s][0][f], acc[s][1][f], acc[s][2][f]);
  };

  WAIT_VM(0);  // drain own prefetch DMAs (slots 0,1 weights)
  issueA(0, af0);
  issueA(1, af1);
  wvm<A2>(); bar_raw(); issueB(2, 2, af2); cons(0, af0);   // kc=0
  wvm<B>();  bar_raw(); issueB(3, 0, af0); cons(1, af1);   // kc=1
#pragma unroll 1
  for (int q = 0; q < 4; ++q) {  // covers kc 2..13
    const int base = 4 + q * 3;  // ikc of first issue
    wvm<B>(); bar_raw(); issueB(base + 0, 1, af1); cons(2, af2);
    wvm<B>(); bar_raw(); issueB(base + 1, 2, af2); cons(0, af0);
    wvm<B>(); bar_raw(); issueB(base + 2, 0, af0); cons(1, af1);
  }
  wvm<B>(); bar_raw(); cons(2, af2);   // kc=14
  wvm<0>(); bar_raw(); cons(0, af0);   // kc=15
}

// x-accumulate for encoder L0 (barrier shadow; normal cached reads).
__device__ __forceinline__ void x_acc(const float* x, int t, const u16* Wp,
                                      int jb, int row0w, int lane,
                                      f32x4* aR, f32x4* aZ, f32x4* aN) {
  const int quad = lane >> 4, n16 = lane & 15;
  const float* xp = x + (size_t)(row0w + n16) * (TT * DIN) +
                    (size_t)t * DIN + quad * 8;
  f32x4 v0 = *(const f32x4*)xp;
  f32x4 v1 = *(const f32x4*)(xp + 4);
  bf16x8 hi, lo;
#pragma unroll
  for (int i = 0; i < 8; ++i) {
    float f = (i < 4) ? v0[i] : v1[i - 4];
    u16 h = (u16)(__float_as_uint(f) >> 16);
    hi[i] = (short)h;
    lo[i] = (short)f2bf_rne(f - bf2f(h));
  }
#pragma unroll
  for (int f = 0; f < 2; ++f)
    mfma_kc9_g(Wp + ((size_t)jb * 2 + f) * 3072, lane, hi, lo,
               aR[f], aZ[f], aN[f]);
}

// Row-group barrier, split arrive/wait (window filled with prefetch/x-phase).
__device__ __forceinline__ void gbar_arrive(unsigned* gen) {
  WAIT_VM(0);  // all this wave's sc1 stores / atomics globally visible
  __syncthreads();
  if (threadIdx.x == 0) atomicAdd(gen, 1u);  // device-scope
}
__device__ __forceinline__ void gbar_wait(unsigned* gen, unsigned target) {
  if (threadIdx.x == 0) {
    while (load_sc_u32w(gen) < target) __builtin_amdgcn_s_sleep(2);
  }
  __syncthreads();
}

// GRU epilogue with register-resident own-tile h; kc-blocked packed store.
__device__ __forceinline__ void gru_epi_reg(
    const float* bi, const float* bh, float (*ht)[4],
    unsigned* hn, int jb, int col0, int row0w, int quad, int n16,
    const f32x4* aR, const f32x4* aZ, const f32x4* aNX, const f32x4* aNH) {
  const size_t hb = ((size_t)(row0w >> 4) * KC_H + jb) * 512;
#pragma unroll
  for (int f = 0; f < 2; ++f) {
    const int col = col0 + f * 16;
    const float bir = bi[col],          bhr = bh[col];
    const float biz = bi[HD + col],     bhz = bh[HD + col];
    const float bin = bi[2 * HD + col], bhn = bh[2 * HD + col];
#pragma unroll
    for (int r = 0; r < 4; ++r) {
      const size_t idx = hb + (quad * 4 + r) * 32 + f * 16 + n16;
      float rr = sigm(aR[f][r] + bir + bhr);
      float zz = sigm(aZ[f][r] + biz + bhz);
      float nn = tanh_(aNX[f][r] + bin + rr * (aNH[f][r] + bhn));
      float hv = (1.f - zz) * nn + zz * ht[f][r];
      ht[f][r] = hv;
      store_h32(hn, idx, hv);
    }
  }
}

__global__ __launch_bounds__(256, 1)
void gru_persistent_kernel(
    const float* x,
    const u16* pkX0, const u16* pkH0, const float* bi0, const float* bh0,
    const u16* pkX1, const u16* pkH1, const float* bi1, const float* bh1,
    const u16* pkD0H, const float* dbi0, const float* dbh0, const float* dW0,
    const u16* pkD1I, const u16* pkD1H, const float* dbi1, const float* dbh1,
    const float* outW, const float* outb, const float* dstart,
    unsigned* h1a, unsigned* h1b, unsigned* h2a, unsigned* h2b,
    float* yfull, float* dout, unsigned* gen) {
  __shared__ u16 ring[3 * 3 * 6144];  // 108 KB: 3-slot triple-stream ring
  const int b = blockIdx.x;
  const int jb = (b & 7) * 2 + ((b >> 3) & 1);  // XCD-local jb
  const int row0 = (b >> 4) * 64;
  const int tid = threadIdx.x, wave = tid >> 6, lane = tid & 63;
  const int quad = lane >> 4, n16 = lane & 15;
  const int row0w = row0 + wave * 16;  // 4 waves = 4 row sub-tiles
  const int col0 = jb * 32 + n16;
  u16* ringb = &ring[0];
  const f32x4 z4 = {0.f, 0.f, 0.f, 0.f};
  const size_t jbs = (size_t)jb * (KC_H * 2 * 3072);  // jb slice base (K=512)
  const u16* pkH0j = pkH0 + jbs;
  const u16* pkX1j = pkX1 + jbs;
  const u16* pkH1j = pkH1 + jbs;
  const u16* pkD0Hj = pkD0H + jbs;
  const u16* pkD1Ij = pkD1I + jbs;
  const u16* pkD1Hj = pkD1H + jbs;
  // Per-row-group barrier counter: one u32 per group, 256-B line separation.
  unsigned* geng = gen + ((b >> 4) << 6);

  unsigned *h1c = h1a, *h1n = h1b;
  unsigned *h2c = h2a, *h2n = h2b;
  float ht1[2][4] = {{0, 0, 0, 0}, {0, 0, 0, 0}};  // own h1 tile (fc, r)
  float ht2[2][4] = {{0, 0, 0, 0}, {0, 0, 0, 0}};  // own h2 tile (fc, r)
  unsigned it = 0;

  // x-phase accumulators for the upcoming encoder step (barrier-shadow).
  f32x4 xR[2] = {z4, z4}, xZ[2] = {z4, z4}, xN[2] = {z4, z4};
  {  // initial prefetch for k=0 single pipe + x-acc(0)
    const u16* Wv1[1] = {pkH0j};
    stageW2<1>(ringb, Wv1, lane, wave);
    x_acc(x, 0, pkX0, jb, row0w, lane, xR, xZ, xN);
  }

  // ---- encoder: 513 skewed phases; ONE merged pipe per step ----
  for (int k = 0; k <= TT; ++k) {
    f32x4 R0[2], Z0[2], NX0[2], NH0[2] = {z4, z4};
    f32x4 R1[2] = {z4, z4}, Z1[2] = {z4, z4}, NX1[2] = {z4, z4}, NH1[2] = {z4, z4};
    if (k < TT) {
      R0[0] = xR[0]; R0[1] = xR[1];
      Z0[0] = xZ[0]; Z0[1] = xZ[1];
      NX0[0] = xN[0]; NX0[1] = xN[1];
    } else {
      R0[0] = z4; R0[1] = z4; Z0[0] = z4; Z0[1] = z4; NX0[0] = z4; NX0[1] = z4;
    }
    if (k > 0 && k < TT) {
      // Triple: L0-h (pkH0*h1), L1-x (pkX1*h1), L1-h (pkH1*h2).
      const unsigned* Ah[2] = {h1c, h2c};
      const u16* Wv[3] = {pkH0j, pkX1j, pkH1j};
      const int ai3[3] = {0, 0, 1};
      f32x4* ac[3][3] = {{R0, Z0, NH0}, {R1, Z1, NX1}, {R1, Z1, NH1}};
      pipePre<3, 2>(ringb, Ah, Wv, ai3, ac, row0w, lane, wave);
    } else if (k == 0) {
      const unsigned* Ah[1] = {h1c};
      const u16* Wv[1] = {pkH0j};
      const int ai1[1] = {0};
      f32x4* ac[1][3] = {{R0, Z0, NH0}};
      pipePre<1, 1>(ringb, Ah, Wv, ai1, ac, row0w, lane, wave);
    } else {  // k == TT: L1-x + L1-h only
      const unsigned* Ah[2] = {h1c, h2c};
      const u16* Wv[2] = {pkX1j, pkH1j};
      const int ai2[2] = {0, 1};
      f32x4* ac[2][3] = {{R1, Z1, NX1}, {R1, Z1, NH1}};
      pipePre<2, 2>(ringb, Ah, Wv, ai2, ac, row0w, lane, wave);
    }
    if (k < TT)
      gru_epi_reg(bi0, bh0, ht1, h1n, jb, col0, row0w, quad, n16,
                  R0, Z0, NX0, NH0);
    if (k > 0)
      gru_epi_reg(bi1, bh1, ht2, h2n, jb, col0, row0w, quad, n16,
                  R1, Z1, NX1, NH1);
    ++it;
    gbar_arrive(geng);
    // ---- barrier shadow: peer-independent work ----
    if (k + 1 < TT) {
      xR[0] = z4; xR[1] = z4; xZ[0] = z4; xZ[1] = z4; xN[0] = z4; xN[1] = z4;
      x_acc(x, k + 1, pkX0, jb, row0w, lane, xR, xZ, xN);
    }
    if (k + 1 < TT) {
      const u16* Wv3[3] = {pkH0j, pkX1j, pkH1j};
      stageW2<3>(ringb, Wv3, lane, wave);
    } else if (k + 1 == TT) {
      const u16* Wv2[2] = {pkX1j, pkH1j};
      stageW2<2>(ringb, Wv2, lane, wave);
    } else {  // k == TT -> next is decoder L0 (single)
      const u16* Wv1[1] = {pkD0Hj};
      stageW2<1>(ringb, Wv1, lane, wave);
    }
    gbar_wait(geng, GRPB * it);
    if (k < TT) { unsigned* t0 = h1c; h1c = h1n; h1n = t0; }
    if (k > 0)  { unsigned* t0 = h2c; h2c = h2n; h2n = t0; }
  }

  // ---- decoder: 96 steps x (L0, L1); y via atomics into yfull[2][BB] ----
  for (int t = 0; t < PP; ++t) {
    {  // dec L0
      f32x4 R[2] = {z4, z4}, Z[2] = {z4, z4}, NH[2] = {z4, z4};
      {
        const unsigned* Ah[1] = {h1c};
        const u16* Wv[1] = {pkD0Hj};
        const int ai1[1] = {0};
        f32x4* ac[1][3] = {{R, Z, NH}};
        pipePre<1, 1>(ringb, Ah, Wv, ai1, ac, row0w, lane, wave);
      }
      float yl[4] = {0, 0, 0, 0};
      if (t > 0) {
        const float* yb = yfull + ((t - 1) & 1) * BB;
#pragma unroll
        for (int r = 0; r < 4; ++r) {
          const float* p = yb + (row0w + quad * 4 + r);
          asm volatile("global_load_dword %0, %1, off sc0 sc1"
                       : "=&v"(yl[r]) : "v"(p) : "memory");
        }
        WAIT_VM(0);
#pragma unroll
        for (int r = 0; r < 4; ++r)
          asm volatile("" : "+v"(yl[r]));
      }
      const float ds0 = dstart[0], ob0 = outb[0];
      const size_t hb = ((size_t)(row0w >> 4) * KC_H + jb) * 512;
#pragma unroll
      for (int f = 0; f < 2; ++f) {
        const int col = col0 + f * 16;
        const float bir = dbi0[col],          bhr = dbh0[col];
        const float biz = dbi0[HD + col],     bhz = dbh0[HD + col];
        const float bin = dbi0[2 * HD + col], bhn = dbh0[2 * HD + col];
        const float w0r = dW0[col], w0z = dW0[HD + col], w0n = dW0[2 * HD + col];
#pragma unroll
        for (int r = 0; r < 4; ++r) {
          const int row = row0w + quad * 4 + r;
          const size_t idx = hb + (quad * 4 + r) * 32 + f * 16 + n16;
          float yv = (t == 0) ? ds0 : (ob0 + yl[r]);
          if (f == 0 && t > 0 && jb == 0 && n16 == 0)
            dout[(size_t)row * PP + (t - 1)] = yv;
          float rr = sigm(R[f][r] + bir + bhr + yv * w0r);
          float zz = sigm(Z[f][r] + biz + bhz + yv * w0z);
          float nn = tanh_(bin + yv * w0n + rr * (NH[f][r] + bhn));
          float hv = (1.f - zz) * nn + zz * ht1[f][r];
          ht1[f][r] = hv;
          store_h32(h1n, idx, hv);
        }
      }
    }
    ++it;
    gbar_arrive(geng);
    {  // barrier shadow: prefetch dual {D1I, D1H}
      const u16* Wv2[2] = {pkD1Ij, pkD1Hj};
      stageW2<2>(ringb, Wv2, lane, wave);
    }
    gbar_wait(geng, GRPB * it);
    {  // dec L1: merged dual pipe (pkD1I*h1n + pkD1H*h2c)
      f32x4 R[2] = {z4, z4}, Z[2] = {z4, z4}, NX[2] = {z4, z4}, NH[2] = {z4, z4};
      {
        const unsigned* Ah[2] = {h1n, h2c};
        const u16* Wv[2] = {pkD1Ij, pkD1Hj};
        const int ai2[2] = {0, 1};
        f32x4* ac[2][3] = {{R, Z, NX}, {R, Z, NH}};
        pipePre<2, 2>(ringb, Ah, Wv, ai2, ac, row0w, lane, wave);
      }
      float vs[4] = {0, 0, 0, 0};
      const size_t hb = ((size_t)(row0w >> 4) * KC_H + jb) * 512;
#pragma unroll
      for (int f = 0; f < 2; ++f) {
        const int col = col0 + f * 16;
        const float bir = dbi1[col],          bhr = dbh1[col];
        const float biz = dbi1[HD + col],     bhz = dbh1[HD + col];
        const float bin = dbi1[2 * HD + col], bhn = dbh1[2 * HD + col];
        const float wo = outW[col];
#pragma unroll
        for (int r = 0; r < 4; ++r) {
          const size_t idx = hb + (quad * 4 + r) * 32 + f * 16 + n16;
          float rr = sigm(R[f][r] + bir + bhr);
          float zz = sigm(Z[f][r] + biz + bhz);
          float nn = tanh_(NX[f][r] + bin + rr * (NH[f][r] + bhn));
          float hv = (1.f - zz) * nn + zz * ht2[f][r];
          ht2[f][r] = hv;
          store_h32(h2n, idx, hv);
          float v = hv * wo;
#pragma unroll
          for (int off = 1; off < 16; off <<= 1) v += __shfl_xor(v, off, 16);
          vs[r] += v;
        }
      }
      float* yw = yfull + (t & 1) * BB;
      float* yz = yfull + ((t - 1) & 1) * BB;
#pragma unroll
      for (int r = 0; r < 4; ++r) {
        const int row = row0w + quad * 4 + r;
        if (n16 == 0) {
          atomicAdd(yw + row, vs[r]);
          // zero last parity (read by dec L0 this iter; rewritten at t+1)
          if (t > 0 && jb == 0) store_sc_f32(yz + row, 0.f);
        }
      }
    }
    ++it;
    gbar_arrive(geng);
    if (t + 1 < PP) {  // barrier shadow: prefetch next dec L0 single
      const u16* Wv1[1] = {pkD0Hj};
      stageW2<1>(ringb, Wv1, lane, wave);
    }
    gbar_wait(geng, GRPB * it);
    { unsigned* t0 = h1c; h1c = h1n; h1n = t0; }
    { unsigned* t0 = h2c; h2c = h2n; h2n = t0; }
  }

  // ---- finalize: y(P-1), group-local (each group's jb==0 block owns its
  // 64 rows; last gbar guarantees peer atomicAdds are visible) ----
  if ((b & 15) == 0 && tid < 64) {
    int row = row0 + tid;
    float v = load_sc_f32w(yfull + ((PP - 1) & 1) * BB + row);
    dout[(size_t)row * PP + (PP - 1)] = outb[0] + v;
  }
}

extern "C" void kernel_launch(void* const* d_in, const int* in_sizes, int n_in,
                              void* d_out, int out_size, void* d_ws, size_t ws_size,
                              hipStream_t stream) {
  const float* x      = (const float*)d_in[0];
  const float* eW_ih0 = (const float*)d_in[1];
  const float* eW_hh0 = (const float*)d_in[2];
  const float* eb_ih0 = (const float*)d_in[3];
  const float* eb_hh0 = (const float*)d_in[4];
  const float* eW_ih1 = (const float*)d_in[5];
  const float* eW_hh1 = (const float*)d_in[6];
  const float* eb_ih1 = (const float*)d_in[7];
  const float* eb_hh1 = (const float*)d_in[8];
  const float* dW_ih0 = (const float*)d_in[9];
  const float* dW_hh0 = (const float*)d_in[10];
  const float* db_ih0 = (const float*)d_in[11];
  const float* db_hh0 = (const float*)d_in[12];
  const float* dW_ih1 = (const float*)d_in[13];
  const float* dW_hh1 = (const float*)d_in[14];
  const float* db_ih1 = (const float*)d_in[15];
  const float* db_hh1 = (const float*)d_in[16];
  const float* outW   = (const float*)d_in[17];
  const float* outb   = (const float*)d_in[18];
  const float* dstart = (const float*)d_in[19];
  float* out = (float*)d_out;

  char* w = (char*)d_ws;
  size_t off = 0;
  auto carve = [&](size_t bytes) -> void* {
    void* p = w + off;
    off = (off + bytes + 255) & ~(size_t)255;
    return p;
  };
  unsigned* h1a = (unsigned*)carve((size_t)BB * HD * 4);
  unsigned* h1b = (unsigned*)carve((size_t)BB * HD * 4);
  unsigned* h2a = (unsigned*)carve((size_t)BB * HD * 4);
  unsigned* h2b = (unsigned*)carve((size_t)BB * HD * 4);
  float* yfull = (float*)carve((size_t)2 * BB * 4);
  unsigned* gen = (unsigned*)carve(4096);  // 16 group counters, 256-B stride
  auto carve_pack = [&](int K) -> u16* {
    return (u16*)carve((size_t)3 * HD * K * 2 * 2);
  };
  u16* pk_e0ih = carve_pack(DIN);
  u16* pk_e0hh = carve_pack(HD);
  u16* pk_e1ih = carve_pack(HD);
  u16* pk_e1hh = carve_pack(HD);
  u16* pk_d0hh = carve_pack(HD);
  u16* pk_d1ih = carve_pack(HD);
  u16* pk_d1hh = carve_pack(HD);

  hipMemsetAsync(h1a, 0, (size_t)BB * HD * 4, stream);
  hipMemsetAsync(h2a, 0, (size_t)BB * HD * 4, stream);
  hipMemsetAsync(yfull, 0, (size_t)2 * BB * 4, stream);
  hipMemsetAsync(gen, 0, 4096, stream);

  auto pack = [&](const float* W, int K, u16* dst) {
    int total = 16 * (K >> 5) * 2 * 6 * 64;
    pack_w_kernel<<<(total + 255) / 256, 256, 0, stream>>>(W, K, dst);
  };
  pack(eW_ih0, DIN, pk_e0ih);
  pack(eW_hh0, HD, pk_e0hh);
  pack(eW_ih1, HD, pk_e1ih);
  pack(eW_hh1, HD, pk_e1hh);
  pack(dW_hh0, HD, pk_d0hh);
  pack(dW_ih1, HD, pk_d1ih);
  pack(dW_hh1, HD, pk_d1hh);

  gru_persistent_kernel<<<NBLK, 256, 0, stream>>>(
      x, pk_e0ih, pk_e0hh, eb_ih0, eb_hh0,
      pk_e1ih, pk_e1hh, eb_ih1, eb_hh1,
      pk_d0hh, db_ih0, db_hh0, dW_ih0,
      pk_d1ih, pk_d1hh, db_ih1, db_hh1,
      outW, outb, dstart,
      h1a, h1b, h2a, h2b,
      yfull, out, gen);
}